// Round 1
// baseline (121.624 us; speedup 1.0000x reference)
//
#include <hip/hip_runtime.h>

// STN bilinear sampler: X [16,256,256,64] f32, theta [16,6] f32 -> out [16,256,256,64] f32
// All dims are powers of two: decompose thread id by shifts.

#define IN_H  256
#define IN_W  256
#define OUT_H 256
#define OUT_W 256
#define NC    64
#define NB    16

__global__ __launch_bounds__(256) void stn_kernel(const float* __restrict__ X,
                                                  const float* __restrict__ theta,
                                                  float* __restrict__ out,
                                                  int total) {
    int t = blockIdx.x * 256 + threadIdx.x;
    const int stride = gridDim.x * 256;
    for (; t < total; t += stride) {
        const int cg    = t & 15;        // 4-channel group (64 ch / 4)
        const int pixel = t >> 4;        // global pixel id: b*65536 + oh*256 + ow
        const int b     = pixel >> 16;
        const int p     = pixel & 65535;
        const int oh    = p >> 8;
        const int ow    = p & 255;

        // linspace(-1,1,256): step 2/255
        const float xc = fmaf((float)ow, 2.0f / 255.0f, -1.0f);
        const float yc = fmaf((float)oh, 2.0f / 255.0f, -1.0f);

        const float* th = theta + b * 6;
        const float sg0 = th[0] * xc + th[1] * yc + th[2];
        const float sg1 = th[3] * xc + th[4] * yc + th[5];
        // source scales by W (not W-1), faithful to reference
        const float x = 0.5f * (sg0 + 1.0f) * (float)IN_W;
        const float y = 0.5f * (sg1 + 1.0f) * (float)IN_H;

        // astype(int32) truncates toward zero; clip AFTER truncation
        const int xi = (int)x;
        const int yi = (int)y;
        const int x0i = min(max(xi,     0), IN_W - 1);
        const int x1i = min(max(xi + 1, 0), IN_W - 1);
        const int y0i = min(max(yi,     0), IN_H - 1);
        const int y1i = min(max(yi + 1, 0), IN_H - 1);

        // weights use the CLIPPED indices cast back to float (faithful)
        const float x0f = (float)x0i, x1f = (float)x1i;
        const float y0f = (float)y0i, y1f = (float)y1i;
        const float wa = (x1f - x) * (y1f - y);
        const float wb = (x1f - x) * (y - y0f);
        const float wc = (x - x0f) * (y1f - y);
        const float wd = (x - x0f) * (y - y0f);

        const size_t base = (size_t)b * (IN_H * IN_W * NC);
        const int co = cg << 2;
        const float* r0 = X + base + ((size_t)y0i * IN_W) * NC + co;
        const float* r1 = X + base + ((size_t)y1i * IN_W) * NC + co;

        const float4 pa = *(const float4*)(r0 + (size_t)x0i * NC);
        const float4 pc = *(const float4*)(r0 + (size_t)x1i * NC);
        const float4 pb = *(const float4*)(r1 + (size_t)x0i * NC);
        const float4 pd = *(const float4*)(r1 + (size_t)x1i * NC);

        float4 o;
        o.x = wa * pa.x + wb * pb.x + wc * pc.x + wd * pd.x;
        o.y = wa * pa.y + wb * pb.y + wc * pc.y + wd * pd.y;
        o.z = wa * pa.z + wb * pb.z + wc * pc.z + wd * pd.z;
        o.w = wa * pa.w + wb * pb.w + wc * pc.w + wd * pd.w;

        *(float4*)(out + (size_t)pixel * NC + co) = o;
    }
}

extern "C" void kernel_launch(void* const* d_in, const int* in_sizes, int n_in,
                              void* d_out, int out_size, void* d_ws, size_t ws_size,
                              hipStream_t stream) {
    const float* X     = (const float*)d_in[0];
    const float* theta = (const float*)d_in[1];
    float* out         = (float*)d_out;

    const int total = NB * OUT_H * OUT_W * (NC / 4);  // 16,777,216 threads of work
    const int blocks = 2048;                          // 256 CU * 8 blocks, grid-stride
    stn_kernel<<<blocks, 256, 0, stream>>>(X, theta, out, total);
}

// Round 2
// 119.216 us; speedup vs baseline: 1.0202x; 1.0202x over previous
//
#include <hip/hip_runtime.h>

// STN bilinear sampler: X [16,256,256,64] f32, theta [16,6] f32 -> out [16,256,256,64] f32
// Tiled: each block owns an 8-row x 32-px output tile of one batch image, so the
// y0/y1 input-row reuse between consecutive output rows stays in L1/L2 instead of
// crossing XCDs (which cost ~2x HBM fetch of X in the 1-D version).

#define IN_H  256
#define IN_W  256
#define OUT_H 256
#define OUT_W 256
#define NC    64
#define NB    16

#define TILE_R 8     // output rows per block
#define TILE_C 32    // output pixels per row per block
// tiles: 16 batches * (256/8=32) * (256/32=8) = 4096 blocks, 16 iters of 256 thr

__global__ __launch_bounds__(256) void stn_kernel(const float* __restrict__ X,
                                                  const float* __restrict__ theta,
                                                  float* __restrict__ out) {
    // bijective XCD-chunked swizzle (4096 % 8 == 0): XCD k gets 512 contiguous tiles
    const int bid = blockIdx.x;
    const int swz = (bid & 7) * 512 + (bid >> 3);

    const int b    = swz >> 8;        // 256 tiles per batch image
    const int tile = swz & 255;
    const int tr   = tile >> 3;       // 32 tile-rows
    const int tc   = tile & 7;        // 8 tile-cols
    const int base_oh = tr << 3;
    const int base_ow = tc << 5;

    const float* th = theta + b * 6;
    const float t0 = th[0], t1 = th[1], t2 = th[2];
    const float t3 = th[3], t4 = th[4], t5 = th[5];

    const size_t xbase = (size_t)b * (IN_H * IN_W * NC);
    const size_t obase = (size_t)b * (OUT_H * OUT_W * NC);

    const int tid = threadIdx.x;

    for (int it = 0; it < 16; ++it) {
        const int idx = it * 256 + tid;          // 0..4095 within tile
        const int cg  = idx & 15;                // 4-channel group
        const int pxl = idx >> 4;                // 0..255 pixel within tile
        const int rr  = pxl >> 5;                // row within tile (row-major sweep)
        const int cc  = pxl & 31;
        const int oh  = base_oh + rr;
        const int ow  = base_ow + cc;

        // linspace(-1,1,256): step 2/255
        const float xc = fmaf((float)ow, 2.0f / 255.0f, -1.0f);
        const float yc = fmaf((float)oh, 2.0f / 255.0f, -1.0f);

        const float sg0 = t0 * xc + t1 * yc + t2;
        const float sg1 = t3 * xc + t4 * yc + t5;
        // source scales by W (not W-1), faithful to reference
        const float x = 0.5f * (sg0 + 1.0f) * (float)IN_W;
        const float y = 0.5f * (sg1 + 1.0f) * (float)IN_H;

        // astype(int32) truncates toward zero; clip AFTER truncation
        const int xi = (int)x;
        const int yi = (int)y;
        const int x0i = min(max(xi,     0), IN_W - 1);
        const int x1i = min(max(xi + 1, 0), IN_W - 1);
        const int y0i = min(max(yi,     0), IN_H - 1);
        const int y1i = min(max(yi + 1, 0), IN_H - 1);

        // weights use the CLIPPED indices cast back to float (faithful)
        const float x0f = (float)x0i, x1f = (float)x1i;
        const float y0f = (float)y0i, y1f = (float)y1i;
        const float wa = (x1f - x) * (y1f - y);
        const float wb = (x1f - x) * (y - y0f);
        const float wc = (x - x0f) * (y1f - y);
        const float wd = (x - x0f) * (y - y0f);

        const int co = cg << 2;
        const float* r0 = X + xbase + ((size_t)y0i * IN_W) * NC + co;
        const float* r1 = X + xbase + ((size_t)y1i * IN_W) * NC + co;

        const float4 pa = *(const float4*)(r0 + (size_t)x0i * NC);
        const float4 pc = *(const float4*)(r0 + (size_t)x1i * NC);
        const float4 pb = *(const float4*)(r1 + (size_t)x0i * NC);
        const float4 pd = *(const float4*)(r1 + (size_t)x1i * NC);

        float4 o;
        o.x = wa * pa.x + wb * pb.x + wc * pc.x + wd * pd.x;
        o.y = wa * pa.y + wb * pb.y + wc * pc.y + wd * pd.y;
        o.z = wa * pa.z + wb * pb.z + wc * pc.z + wd * pd.z;
        o.w = wa * pa.w + wb * pb.w + wc * pc.w + wd * pd.w;

        *(float4*)(out + obase + (((size_t)oh * OUT_W + ow) * NC) + co) = o;
    }
}

extern "C" void kernel_launch(void* const* d_in, const int* in_sizes, int n_in,
                              void* d_out, int out_size, void* d_ws, size_t ws_size,
                              hipStream_t stream) {
    const float* X     = (const float*)d_in[0];
    const float* theta = (const float*)d_in[1];
    float* out         = (float*)d_out;

    const int blocks = NB * (OUT_H / TILE_R) * (OUT_W / TILE_C);  // 4096
    stn_kernel<<<blocks, 256, 0, stream>>>(X, theta, out);
}

// Round 4
// 83.533 us; speedup vs baseline: 1.4560x; 1.4272x over previous
//
#include <hip/hip_runtime.h>

// STN bilinear sampler: X [16,256,256,64] f32, theta [16,6] f32 -> out [16,256,256,64] f32
// 16x32 output tiles: boundary over-fetch (rows+cols read by neighbors) drops to ~1.14x.
// 2048 blocks = 8 blocks/CU exactly resident; XCD-chunked swizzle gives each XCD 2 images.
// Nontemporal stores keep the out stream from evicting X in L2/L3.

#define IN_H  256
#define IN_W  256
#define OUT_H 256
#define OUT_W 256
#define NC    64
#define NB    16

#define TILE_R 16    // output rows per block
#define TILE_C 32    // output pixels per row per block
// tiles: 16 batches * (256/16=16) * (256/32=8) = 2048 blocks, 32 iters of 256 thr

typedef float floatx4 __attribute__((ext_vector_type(4)));  // native vec for nontemporal store

__global__ __launch_bounds__(256) void stn_kernel(const float* __restrict__ X,
                                                  const float* __restrict__ theta,
                                                  float* __restrict__ out) {
    // bijective XCD-chunked swizzle (2048 % 8 == 0): XCD k gets 256 contiguous tiles
    // = exactly 2 batch images, all resident at once (8 blocks/CU * 32 CU/XCD = 256).
    const int bid = blockIdx.x;
    const int swz = (bid & 7) * 256 + (bid >> 3);

    const int b    = swz >> 7;        // 128 tiles per batch image
    const int tile = swz & 127;
    const int tr   = tile >> 3;       // 16 tile-rows
    const int tc   = tile & 7;        // 8 tile-cols
    const int base_oh = tr << 4;
    const int base_ow = tc << 5;

    const float* th = theta + b * 6;
    const float t0 = th[0], t1 = th[1], t2 = th[2];
    const float t3 = th[3], t4 = th[4], t5 = th[5];

    const size_t xbase = (size_t)b * (IN_H * IN_W * NC);
    const size_t obase = (size_t)b * (OUT_H * OUT_W * NC);

    const int tid = threadIdx.x;

#pragma unroll 2
    for (int it = 0; it < 32; ++it) {
        const int idx = it * 256 + tid;          // 0..8191 within tile
        const int cg  = idx & 15;                // 4-channel group
        const int pxl = idx >> 4;                // 0..511 pixel within tile
        const int rr  = pxl >> 5;                // row within tile (row-major sweep)
        const int cc  = pxl & 31;
        const int oh  = base_oh + rr;
        const int ow  = base_ow + cc;

        // linspace(-1,1,256): step 2/255
        const float xc = fmaf((float)ow, 2.0f / 255.0f, -1.0f);
        const float yc = fmaf((float)oh, 2.0f / 255.0f, -1.0f);

        const float sg0 = t0 * xc + t1 * yc + t2;
        const float sg1 = t3 * xc + t4 * yc + t5;
        // source scales by W (not W-1), faithful to reference
        const float x = 0.5f * (sg0 + 1.0f) * (float)IN_W;
        const float y = 0.5f * (sg1 + 1.0f) * (float)IN_H;

        // astype(int32) truncates toward zero; clip AFTER truncation
        const int xi = (int)x;
        const int yi = (int)y;
        const int x0i = min(max(xi,     0), IN_W - 1);
        const int x1i = min(max(xi + 1, 0), IN_W - 1);
        const int y0i = min(max(yi,     0), IN_H - 1);
        const int y1i = min(max(yi + 1, 0), IN_H - 1);

        // weights use the CLIPPED indices cast back to float (faithful)
        const float x0f = (float)x0i, x1f = (float)x1i;
        const float y0f = (float)y0i, y1f = (float)y1i;
        const float wa = (x1f - x) * (y1f - y);
        const float wb = (x1f - x) * (y - y0f);
        const float wc = (x - x0f) * (y1f - y);
        const float wd = (x - x0f) * (y - y0f);

        const int co = cg << 2;
        const float* r0 = X + xbase + ((size_t)y0i * IN_W) * NC + co;
        const float* r1 = X + xbase + ((size_t)y1i * IN_W) * NC + co;

        const float4 pa = *(const float4*)(r0 + (size_t)x0i * NC);
        const float4 pc = *(const float4*)(r0 + (size_t)x1i * NC);
        const float4 pb = *(const float4*)(r1 + (size_t)x0i * NC);
        const float4 pd = *(const float4*)(r1 + (size_t)x1i * NC);

        floatx4 o;
        o.x = wa * pa.x + wb * pb.x + wc * pc.x + wd * pd.x;
        o.y = wa * pa.y + wb * pb.y + wc * pc.y + wd * pd.y;
        o.z = wa * pa.z + wb * pb.z + wc * pc.z + wd * pd.z;
        o.w = wa * pa.w + wb * pb.w + wc * pc.w + wd * pd.w;

        floatx4* dst = (floatx4*)(out + obase + (((size_t)oh * OUT_W + ow) * NC) + co);
        __builtin_nontemporal_store(o, dst);
    }
}

extern "C" void kernel_launch(void* const* d_in, const int* in_sizes, int n_in,
                              void* d_out, int out_size, void* d_ws, size_t ws_size,
                              hipStream_t stream) {
    const float* X     = (const float*)d_in[0];
    const float* theta = (const float*)d_in[1];
    float* out         = (float*)d_out;

    const int blocks = NB * (OUT_H / TILE_R) * (OUT_W / TILE_C);  // 2048
    stn_kernel<<<blocks, 256, 0, stream>>>(X, theta, out);
}

// Round 5
// 80.128 us; speedup vs baseline: 1.5179x; 1.0425x over previous
//
#include <hip/hip_runtime.h>

// STN bilinear sampler: X [16,256,256,64] f32, theta [16,6] f32 -> out [16,256,256,64] f32
// 32x32 output tiles (over-fetch ~1.07x), 1024 blocks = 4/CU, XCD-chunked swizzle,
// nontemporal stores keep X resident in L2/L3 (R4: FETCH 125MB < X's 268MB proves it).

#define IN_H  256
#define IN_W  256
#define OUT_H 256
#define OUT_W 256
#define NC    64
#define NB    16

#define TILE_R 32    // output rows per block
#define TILE_C 32    // output pixels per row per block
// tiles: 16 batches * (256/32=8) * (256/32=8) = 1024 blocks, 64 iters of 256 thr

typedef float floatx4 __attribute__((ext_vector_type(4)));  // native vec for nontemporal store

__global__ __launch_bounds__(256) void stn_kernel(const float* __restrict__ X,
                                                  const float* __restrict__ theta,
                                                  float* __restrict__ out) {
    // bijective XCD-chunked swizzle (1024 % 8 == 0): XCD k gets 128 contiguous tiles
    // = exactly 2 batch images per XCD.
    const int bid = blockIdx.x;
    const int swz = (bid & 7) * 128 + (bid >> 3);

    const int b    = swz >> 6;        // 64 tiles per batch image
    const int tile = swz & 63;
    const int tr   = tile >> 3;       // 8 tile-rows
    const int tc   = tile & 7;        // 8 tile-cols
    const int base_oh = tr << 5;
    const int base_ow = tc << 5;

    const float* th = theta + b * 6;
    const float t0 = th[0], t1 = th[1], t2 = th[2];
    const float t3 = th[3], t4 = th[4], t5 = th[5];

    const size_t xbase = (size_t)b * (IN_H * IN_W * NC);
    const size_t obase = (size_t)b * (OUT_H * OUT_W * NC);

    const int tid = threadIdx.x;

#pragma unroll 4
    for (int it = 0; it < 64; ++it) {
        const int idx = it * 256 + tid;          // 0..16383 within tile
        const int cg  = idx & 15;                // 4-channel group
        const int pxl = idx >> 4;                // 0..1023 pixel within tile
        const int rr  = pxl >> 5;                // row within tile (row-major sweep)
        const int cc  = pxl & 31;
        const int oh  = base_oh + rr;
        const int ow  = base_ow + cc;

        // linspace(-1,1,256): step 2/255
        const float xc = fmaf((float)ow, 2.0f / 255.0f, -1.0f);
        const float yc = fmaf((float)oh, 2.0f / 255.0f, -1.0f);

        const float sg0 = t0 * xc + t1 * yc + t2;
        const float sg1 = t3 * xc + t4 * yc + t5;
        // source scales by W (not W-1), faithful to reference
        const float x = 0.5f * (sg0 + 1.0f) * (float)IN_W;
        const float y = 0.5f * (sg1 + 1.0f) * (float)IN_H;

        // astype(int32) truncates toward zero; clip AFTER truncation
        const int xi = (int)x;
        const int yi = (int)y;
        const int x0i = min(max(xi,     0), IN_W - 1);
        const int x1i = min(max(xi + 1, 0), IN_W - 1);
        const int y0i = min(max(yi,     0), IN_H - 1);
        const int y1i = min(max(yi + 1, 0), IN_H - 1);

        // weights use the CLIPPED indices cast back to float (faithful)
        const float x0f = (float)x0i, x1f = (float)x1i;
        const float y0f = (float)y0i, y1f = (float)y1i;
        const float wa = (x1f - x) * (y1f - y);
        const float wb = (x1f - x) * (y - y0f);
        const float wc = (x - x0f) * (y1f - y);
        const float wd = (x - x0f) * (y - y0f);

        const int co = cg << 2;
        const float* r0 = X + xbase + ((size_t)y0i * IN_W) * NC + co;
        const float* r1 = X + xbase + ((size_t)y1i * IN_W) * NC + co;

        const float4 pa = *(const float4*)(r0 + (size_t)x0i * NC);
        const float4 pc = *(const float4*)(r0 + (size_t)x1i * NC);
        const float4 pb = *(const float4*)(r1 + (size_t)x0i * NC);
        const float4 pd = *(const float4*)(r1 + (size_t)x1i * NC);

        floatx4 o;
        o.x = wa * pa.x + wb * pb.x + wc * pc.x + wd * pd.x;
        o.y = wa * pa.y + wb * pb.y + wc * pc.y + wd * pd.y;
        o.z = wa * pa.z + wb * pb.z + wc * pc.z + wd * pd.z;
        o.w = wa * pa.w + wb * pb.w + wc * pc.w + wd * pd.w;

        floatx4* dst = (floatx4*)(out + obase + (((size_t)oh * OUT_W + ow) * NC) + co);
        __builtin_nontemporal_store(o, dst);
    }
}

extern "C" void kernel_launch(void* const* d_in, const int* in_sizes, int n_in,
                              void* d_out, int out_size, void* d_ws, size_t ws_size,
                              hipStream_t stream) {
    const float* X     = (const float*)d_in[0];
    const float* theta = (const float*)d_in[1];
    float* out         = (float*)d_out;

    const int blocks = NB * (OUT_H / TILE_R) * (OUT_W / TILE_C);  // 1024
    stn_kernel<<<blocks, 256, 0, stream>>>(X, theta, out);
}